// Round 1
// 217.731 us; speedup vs baseline: 1.0139x; 1.0139x over previous
//
#include <hip/hip_runtime.h>

// SpikeFP32LayerNorm: LayerNorm (no affine) over rows of (8192, 4096) fp32,
// statistics + normalization in FP64 per the reference circuit:
//   mean = sum(x64)/N ; c = x64 - mean ; var = sum(c*c)/N ; vpe = var + 1e-6
//   y = 1/vpe ; 5x NR: y = 0.5*y*(3 - vpe*y*y) ; out = fp32(c * y)
//
// v2: FOUR waves per row (256-thread block per row) instead of one wave/row.
//   - payload drops from 16 vec4 (64 VGPR) to 4 vec4 (16 VGPR) per lane
//     -> total ~48 VGPR -> 8 waves/SIMD occupancy (was ~4-5) for latency hiding
//   - per-wave serial chains (pass1/pass2/allreduce) shrink 4x
//   - cross-wave reduction via 64 B LDS, 2 barriers total
// Nontemporal vec4 loads/stores (stream-once data).

#define LN_BATCH   8192
#define LN_N       4096
#define LN_THREADS 256            // 4 waves, one row per block
#define LN_WAVES   4
#define LN_F4PT    4              // vec4 per lane: 16 elems/lane
#define LN_EPS     1e-6

typedef float vfloat4 __attribute__((ext_vector_type(4)));

__device__ __forceinline__ double wave_allreduce_add(double s) {
#pragma unroll
    for (int off = 1; off < 64; off <<= 1)
        s += __shfl_xor(s, off, 64);
    return s;
}

__global__ __launch_bounds__(LN_THREADS, 8)
void spike_layernorm_kernel(const float* __restrict__ x, float* __restrict__ out) {
    const int wave = threadIdx.x >> 6;
    const int lane = threadIdx.x & 63;
    const int row  = blockIdx.x;

    __shared__ double red[2][LN_WAVES];

    const vfloat4* __restrict__ xr =
        reinterpret_cast<const vfloat4*>(x + (size_t)row * LN_N);
    vfloat4* __restrict__ orow =
        reinterpret_cast<vfloat4*>(out + (size_t)row * LN_N);

    // Each wave owns a contiguous quarter-row (256 vec4); lane-coalesced.
    const int base = wave * (LN_N / 4 / LN_WAVES) + lane;

    vfloat4 v[LN_F4PT];
#pragma unroll
    for (int i = 0; i < LN_F4PT; ++i)
        v[i] = __builtin_nontemporal_load(&xr[base + i * 64]);

    // ---- Pass 1: FP64 sum -> mean ----
    double s0 = 0.0, s1 = 0.0;
#pragma unroll
    for (int i = 0; i < LN_F4PT; ++i) {
        s0 += (double)v[i].x + (double)v[i].y;
        s1 += (double)v[i].z + (double)v[i].w;
    }
    double s = wave_allreduce_add(s0 + s1);
    if (lane == 0) red[0][wave] = s;
    __syncthreads();
    const double mean =
        ((red[0][0] + red[0][1]) + (red[0][2] + red[0][3])) * (1.0 / LN_N);

    // ---- Pass 2: FP64 sum of (x-mean)^2 -> var ----
    double q0 = 0.0, q1 = 0.0;
#pragma unroll
    for (int i = 0; i < LN_F4PT; ++i) {
        double d;
        d = (double)v[i].x - mean; q0 += d * d;
        d = (double)v[i].y - mean; q1 += d * d;
        d = (double)v[i].z - mean; q0 += d * d;
        d = (double)v[i].w - mean; q1 += d * d;
    }
    double q = wave_allreduce_add(q0 + q1);
    if (lane == 0) red[1][wave] = q;
    __syncthreads();
    const double var =
        ((red[1][0] + red[1][1]) + (red[1][2] + red[1][3])) * (1.0 / LN_N);

    // ---- NR rsqrt-free reciprocal refinement (wave-uniform on all lanes) ----
    const double vpe = var + LN_EPS;
    double y = 1.0 / vpe;
#pragma unroll
    for (int it = 0; it < 5; ++it)
        y = 0.5 * y * (3.0 - vpe * (y * y));

    // ---- Pass 3: out = fp32((x64 - mean) * y) ----
#pragma unroll
    for (int i = 0; i < LN_F4PT; ++i) {
        vfloat4 o;
        o.x = (float)(((double)v[i].x - mean) * y);
        o.y = (float)(((double)v[i].y - mean) * y);
        o.z = (float)(((double)v[i].z - mean) * y);
        o.w = (float)(((double)v[i].w - mean) * y);
        __builtin_nontemporal_store(o, &orow[base + i * 64]);
    }
}

extern "C" void kernel_launch(void* const* d_in, const int* in_sizes, int n_in,
                              void* d_out, int out_size, void* d_ws, size_t ws_size,
                              hipStream_t stream) {
    const float* x = (const float*)d_in[0];
    float* out = (float*)d_out;
    spike_layernorm_kernel<<<LN_BATCH, LN_THREADS, 0, stream>>>(x, out);
}

// Round 2
// 217.068 us; speedup vs baseline: 1.0170x; 1.0031x over previous
//
#include <hip/hip_runtime.h>

// SpikeFP32LayerNorm: LayerNorm (no affine) over rows of (8192, 4096) fp32,
// statistics + normalization in FP64 per the reference circuit:
//   mean = sum(x64)/N ; c = x64 - mean ; var = sum(c*c)/N ; vpe = var + 1e-6
//   y = 1/vpe ; 5x NR: y = 0.5*y*(3 - vpe*y*y) ; out = fp32(c * y)
//
// v3: row-pipelined persistent blocks (de-convoy the VMEM pipe).
//   v2 issued all loads at block start, then went VMEM-silent for ~3000 cy
//   (reduce chains + barriers + NR), then burst stores -- co-resident blocks
//   stay phase-aligned through the barriers, so the CU alternates between
//   memory-burst and memory-idle. v3: grid=2048 persistent blocks, 4 rows
//   each; row r+1's 4 vec4 loads are issued BEFORE row r's compute, hiding
//   next-row HBM latency under the current row's compute/reduce chain.
//   __launch_bounds__(256,7): VGPR cap ~72 (payload 32 + temps ~30) -- no
//   spill risk, still 8 waves/EU if allocator lands <=64.
// Accumulation order identical to v2 (bit-exact, absmax 0.0).

#define LN_BATCH   8192
#define LN_N       4096
#define LN_THREADS 256            // 4 waves, one row at a time per block
#define LN_WAVES   4
#define LN_F4PT    4              // vec4 per lane: 16 elems/lane
#define LN_GRID    2048           // persistent blocks (Guideline 11)
#define LN_ROWS_PB (LN_BATCH / LN_GRID)   // 4 rows per block
#define LN_EPS     1e-6

typedef float vfloat4 __attribute__((ext_vector_type(4)));

__device__ __forceinline__ double wave_allreduce_add(double s) {
#pragma unroll
    for (int off = 1; off < 64; off <<= 1)
        s += __shfl_xor(s, off, 64);
    return s;
}

__global__ __launch_bounds__(LN_THREADS, 7)
void spike_layernorm_kernel(const float* __restrict__ x, float* __restrict__ out) {
    const int wave = threadIdx.x >> 6;
    const int lane = threadIdx.x & 63;
    // vec4 index within the row: each wave owns a contiguous quarter (256 vec4)
    const int vbase = wave * (LN_N / 4 / LN_WAVES) + lane;

    __shared__ double red[2][LN_WAVES];

    // Prologue: load row blockIdx.x
    vfloat4 v[LN_F4PT];
    {
        const vfloat4* __restrict__ xr =
            reinterpret_cast<const vfloat4*>(x + (size_t)blockIdx.x * LN_N);
#pragma unroll
        for (int i = 0; i < LN_F4PT; ++i)
            v[i] = __builtin_nontemporal_load(&xr[vbase + i * 64]);
    }

#pragma unroll
    for (int it = 0; it < LN_ROWS_PB; ++it) {
        const int r = blockIdx.x + it * LN_GRID;

        // ---- Prefetch row r+LN_GRID: in flight across the entire compute
        //      chain below (loads are older than any dependent use). ----
        vfloat4 w[LN_F4PT];
        if (it + 1 < LN_ROWS_PB) {
            const vfloat4* __restrict__ xn =
                reinterpret_cast<const vfloat4*>(x + (size_t)(r + LN_GRID) * LN_N);
#pragma unroll
            for (int i = 0; i < LN_F4PT; ++i)
                w[i] = __builtin_nontemporal_load(&xn[vbase + i * 64]);
        }

        // ---- Pass 1: FP64 sum -> mean ----
        double s0 = 0.0, s1 = 0.0;
#pragma unroll
        for (int i = 0; i < LN_F4PT; ++i) {
            s0 += (double)v[i].x + (double)v[i].y;
            s1 += (double)v[i].z + (double)v[i].w;
        }
        double s = wave_allreduce_add(s0 + s1);
        if (lane == 0) red[0][wave] = s;
        __syncthreads();
        const double mean =
            ((red[0][0] + red[0][1]) + (red[0][2] + red[0][3])) * (1.0 / LN_N);

        // ---- Pass 2: FP64 sum of (x-mean)^2 -> var ----
        double q0 = 0.0, q1 = 0.0;
#pragma unroll
        for (int i = 0; i < LN_F4PT; ++i) {
            double d;
            d = (double)v[i].x - mean; q0 += d * d;
            d = (double)v[i].y - mean; q1 += d * d;
            d = (double)v[i].z - mean; q0 += d * d;
            d = (double)v[i].w - mean; q1 += d * d;
        }
        double q = wave_allreduce_add(q0 + q1);
        if (lane == 0) red[1][wave] = q;
        __syncthreads();
        const double var =
            ((red[1][0] + red[1][1]) + (red[1][2] + red[1][3])) * (1.0 / LN_N);

        // ---- NR reciprocal refinement (wave-uniform on all lanes) ----
        const double vpe = var + LN_EPS;
        double y = 1.0 / vpe;
#pragma unroll
        for (int nr = 0; nr < 5; ++nr)
            y = 0.5 * y * (3.0 - vpe * (y * y));

        // ---- Pass 3: out = fp32((x64 - mean) * y) ----
        vfloat4* __restrict__ orow =
            reinterpret_cast<vfloat4*>(out + (size_t)r * LN_N);
#pragma unroll
        for (int i = 0; i < LN_F4PT; ++i) {
            vfloat4 o;
            o.x = (float)(((double)v[i].x - mean) * y);
            o.y = (float)(((double)v[i].y - mean) * y);
            o.z = (float)(((double)v[i].z - mean) * y);
            o.w = (float)(((double)v[i].w - mean) * y);
            __builtin_nontemporal_store(o, &orow[vbase + i * 64]);
        }

        // Rotate prefetched row into place (SSA-renamed, no real moves).
        if (it + 1 < LN_ROWS_PB) {
#pragma unroll
            for (int i = 0; i < LN_F4PT; ++i) v[i] = w[i];
        }
    }
}

extern "C" void kernel_launch(void* const* d_in, const int* in_sizes, int n_in,
                              void* d_out, int out_size, void* d_ws, size_t ws_size,
                              hipStream_t stream) {
    const float* x = (const float*)d_in[0];
    float* out = (float*)d_out;
    spike_layernorm_kernel<<<LN_GRID, LN_THREADS, 0, stream>>>(x, out);
}